// Round 1
// baseline (397.784 us; speedup 1.0000x reference)
//
#include <hip/hip_runtime.h>
#include <math.h>

#define B_DIM 16
#define T_DIM 2048
#define D_DIM 1024
#define CHUNK 256
#define WARM  128
#define NCHUNK (T_DIM / CHUNK)   // 8
#define DTILES (D_DIM / 256)     // 4

__device__ __forceinline__ float rcp_f (float v){ return __builtin_amdgcn_rcpf(v);  }
__device__ __forceinline__ float exp2_f(float v){ return __builtin_amdgcn_exp2f(v); }
__device__ __forceinline__ float sqrt_f(float v){ return __builtin_amdgcn_sqrtf(v); }
__device__ __forceinline__ float softplus_f(float v){
    // ln(1+e^v), overflow-safe; only used once per thread
    return fmaxf(v, 0.0f) + log1pf(__expf(-fabsf(v)));
}

// tanh(a) = 1 - 2/(1 + e^{2a}); we fold 2*sigma*log2(e) into the exp2 arg so each
// gate is: exp2 -> rcp -> fma.  Valid for all signs; rcp(inf)=0 gives the right limit.

__global__ __launch_bounds__(256) void gelu130_kernel(
    const float* __restrict__ x,
    const float* __restrict__ s_logit_decay_l,
    const float* __restrict__ s_log_sigma_l,
    const float* __restrict__ s_log_alpha_l,
    const float* __restrict__ s_log_sigma_g,
    const float* __restrict__ s_log_alpha_g,
    const float* __restrict__ ema_mean_g,
    const float* __restrict__ ema_sq_g,
    float* __restrict__ out)
{
    const float LOG2E = 1.4426950408889634f;

    const int bid   = blockIdx.x;
    const int dtile = bid % DTILES;
    const int c     = (bid / DTILES) % NCHUNK;
    const int b     = bid / (DTILES * NCHUNK);
    const int d     = dtile * 256 + threadIdx.x;

    // ---- scalar-derived constants (broadcast loads, negligible) ----
    const float dl      = 1.0f / (1.0f + __expf(-s_logit_decay_l[0]));
    const float ql      = 1.0f - dl;
    const float sigma_l = softplus_f(s_log_sigma_l[0]);
    const float alpha_l = softplus_f(s_log_alpha_l[0]);
    const float sigma_g = softplus_f(s_log_sigma_g[0]);
    const float alpha_g = softplus_f(s_log_alpha_g[0]);

    const float c1l = 2.0f * sigma_l * LOG2E;        // tanh arg scale (local)
    const float gA  = -2.0f * alpha_l;               // gate = gB + gA*rcp(1+e)
    const float gB  = 1.0f + alpha_l;

    // ---- per-d global-gate constants ----
    const float mg   = ema_mean_g[d];
    const float sgv  = ema_sq_g[d];
    const float varg = fmaxf(sgv - mg * mg, 1e-4f);
    const float invg = 1.0f / (sqrtf(varg) + 1e-5f);
    const float cg   = 2.0f * sigma_g * LOG2E * invg; // folds inv-denom into tanh arg
    const float gGA  = -2.0f * alpha_g;
    const float gGB  = 1.0f + alpha_g;

    const float C3 = 2.0f * 0.7978845608028654f * LOG2E; // gelu tanh arg scale

    // gelu(y)*post_gate(xt)
    auto emit = [&](float xt, float gate) -> float {
        float y    = xt * gate;
        float y2   = y * y;
        float uarg = C3 * y * fmaf(0.044715f, y2, 1.0f);
        float r2   = rcp_f(1.0f + exp2_f(uarg));
        float gelu = y * (1.0f - r2);                 // 0.5*y*(1+tanh(u))
        float ag   = cg * fabsf(xt - mg);
        float r3   = rcp_f(1.0f + exp2_f(ag));
        float pg   = fmaf(gGA, r3, gGB);
        return gelu * pg;
    };

    const size_t base = ((size_t)b * T_DIM) * D_DIM + d;
    const int ms = c * CHUNK;            // main range [ms, me)
    const int me = ms + CHUNK;
    const int t0 = (c == 0) ? 0 : ms - WARM;

    const float* px = x + base + (size_t)t0 * D_DIM;

    // chain (re)start: treat t0 as t=0 of a fresh chain; truncation error ~0.9^128
    float x0   = *px; px += D_DIM;
    float mean = x0;
    float sq   = x0 * x0;

    int tstart;
    if (c == 0) {
        out[base] = emit(x0, 1.0f);      // t = 0: pre_gate == 1 exactly
        tstart = 1;
    } else {
        #pragma unroll 4
        for (int t = t0 + 1; t < ms; ++t) {   // warm-up: EMA only
            float xt = *px; px += D_DIM;
            mean = fmaf(dl, mean, ql * xt);
            sq   = fmaf(dl, sq,   ql * (xt * xt));
        }
        tstart = ms;
    }

    float* pout = out + base + (size_t)tstart * D_DIM;

    #pragma unroll 2
    for (int t = tstart; t < me; ++t) {
        float xt  = *px; px += D_DIM;
        // local gate from carry BEFORE incorporating xt
        float var  = fmaxf(fmaf(-mean, mean, sq), 1e-4f);
        float rs   = rcp_f(sqrt_f(var) + 1e-5f);
        float a    = c1l * fabsf(xt - mean) * rs;
        float r1   = rcp_f(1.0f + exp2_f(a));
        float gate = fmaf(gA, r1, gB);

        *pout = emit(xt, gate); pout += D_DIM;

        mean = fmaf(dl, mean, ql * xt);
        sq   = fmaf(dl, sq,   ql * (xt * xt));
    }
}

extern "C" void kernel_launch(void* const* d_in, const int* in_sizes, int n_in,
                              void* d_out, int out_size, void* d_ws, size_t ws_size,
                              hipStream_t stream) {
    const float* x  = (const float*)d_in[0];
    // dict order: x, logit_decay_l, log_sigma_l, log_alpha_l,
    //             logit_decay_g(unused), log_sigma_g, log_alpha_g, ema_mean_g, ema_sq_g
    gelu130_kernel<<<dim3(B_DIM * NCHUNK * DTILES), dim3(256), 0, stream>>>(
        x,
        (const float*)d_in[1],
        (const float*)d_in[2],
        (const float*)d_in[3],
        (const float*)d_in[5],
        (const float*)d_in[6],
        (const float*)d_in[7],
        (const float*)d_in[8],
        (float*)d_out);
}

// Round 5
// 281.461 us; speedup vs baseline: 1.4133x; 1.4133x over previous
//
#include <hip/hip_runtime.h>
#include <math.h>

#define B_DIM 16
#define T_DIM 2048
#define D_DIM 1024
#define CHUNK 128
#define LOOKBACK 128              // init sample + 127 warm EMA steps
#define NCHUNK (T_DIM / CHUNK)    // 16
#define DTILES (D_DIM / 256)      // 4
#define G 8                       // prefetch group depth

__device__ __forceinline__ float rcp_f (float v){ return __builtin_amdgcn_rcpf(v);  }
__device__ __forceinline__ float exp2_f(float v){ return __builtin_amdgcn_exp2f(v); }
__device__ __forceinline__ float sqrt_f(float v){ return __builtin_amdgcn_sqrtf(v); }
__device__ __forceinline__ float softplus_f(float v){
    return fmaxf(v, 0.0f) + log1pf(__expf(-fabsf(v)));
}

// tanh(a) = 1 - 2/(1 + e^{2a}); 2*sigma*log2(e) folded into the exp2 arg:
// each gate costs exp2 -> rcp -> fma.  rcp(inf)=0 gives the correct saturation.

__global__ __launch_bounds__(256) void gelu130_kernel(
    const float* __restrict__ x,
    const float* __restrict__ s_logit_decay_l,
    const float* __restrict__ s_log_sigma_l,
    const float* __restrict__ s_log_alpha_l,
    const float* __restrict__ s_log_sigma_g,
    const float* __restrict__ s_log_alpha_g,
    const float* __restrict__ ema_mean_g,
    const float* __restrict__ ema_sq_g,
    float* __restrict__ out)
{
    const float LOG2E = 1.4426950408889634f;

    const int bid   = blockIdx.x;
    const int dtile = bid % DTILES;
    const int c     = (bid / DTILES) % NCHUNK;
    const int b     = bid / (DTILES * NCHUNK);
    const int d     = dtile * 256 + threadIdx.x;

    // ---- scalar-derived constants ----
    const float dl      = 1.0f / (1.0f + __expf(-s_logit_decay_l[0]));
    const float ql      = 1.0f - dl;
    const float sigma_l = softplus_f(s_log_sigma_l[0]);
    const float alpha_l = softplus_f(s_log_alpha_l[0]);
    const float sigma_g = softplus_f(s_log_sigma_g[0]);
    const float alpha_g = softplus_f(s_log_alpha_g[0]);

    const float c1l = 2.0f * sigma_l * LOG2E;
    const float gA  = -2.0f * alpha_l;
    const float gB  = 1.0f + alpha_l;

    // ---- per-d global-gate constants ----
    const float mg   = ema_mean_g[d];
    const float sgv  = ema_sq_g[d];
    const float varg = fmaxf(sgv - mg * mg, 1e-4f);
    const float invg = 1.0f / (sqrtf(varg) + 1e-5f);
    const float cg   = 2.0f * sigma_g * LOG2E * invg;
    const float gGA  = -2.0f * alpha_g;
    const float gGB  = 1.0f + alpha_g;

    const float C3 = 2.0f * 0.7978845608028654f * LOG2E;

    auto emit = [&](float xt, float gate) -> float {
        float y    = xt * gate;
        float y2   = y * y;
        float uarg = C3 * y * fmaf(0.044715f, y2, 1.0f);
        float r2   = rcp_f(1.0f + exp2_f(uarg));
        float gelu = y * (1.0f - r2);
        float ag   = cg * fabsf(xt - mg);
        float r3   = rcp_f(1.0f + exp2_f(ag));
        float pg   = fmaf(gGA, r3, gGB);
        return gelu * pg;
    };

    const size_t base = ((size_t)b * T_DIM) * D_DIM + d;
    const int ms = c * CHUNK;

    const float* px;
    float mean, sq;

    if (c == 0) {
        // init from t=0; generic main loop then regenerates gate==1 at t=0
        // (mean==x0, sq==x0^2  ->  z==0  ->  gate==1 exactly)
        float x0 = x[base];
        mean = x0; sq = x0 * x0;
        px = x + base;                       // main starts at t = 0
    } else {
        // lookback window [ms-128, ms): element 0 is chain init, 127 EMA steps.
        px = x + base + (size_t)(ms - LOOKBACK) * D_DIM;
        {   // first group: init + 7 warm steps
            float v[G];
            #pragma unroll
            for (int i = 0; i < G; ++i) v[i] = px[i * D_DIM];
            px += G * D_DIM;
            mean = v[0]; sq = v[0] * v[0];
            #pragma unroll
            for (int i = 1; i < G; ++i) {
                mean = fmaf(dl, mean, ql * v[i]);
                sq   = fmaf(dl, sq,   ql * (v[i] * v[i]));
            }
        }
        for (int g = 1; g < LOOKBACK / G; ++g) {   // 15 more groups of 8
            float v[G];
            #pragma unroll
            for (int i = 0; i < G; ++i) v[i] = px[i * D_DIM];
            px += G * D_DIM;
            #pragma unroll
            for (int i = 0; i < G; ++i) {
                mean = fmaf(dl, mean, ql * v[i]);
                sq   = fmaf(dl, sq,   ql * (v[i] * v[i]));
            }
        }
    }

    float* pout = out + base + (size_t)ms * D_DIM;

    // ---- main loop: CHUNK steps, double-buffered groups of G ----
    float buf[G];
    #pragma unroll
    for (int i = 0; i < G; ++i) buf[i] = px[i * D_DIM];
    px += G * D_DIM;

    for (int g = 0; g < CHUNK / G - 1; ++g) {
        float nbuf[G];
        #pragma unroll
        for (int i = 0; i < G; ++i) nbuf[i] = px[i * D_DIM];   // in flight over compute
        px += G * D_DIM;

        #pragma unroll
        for (int i = 0; i < G; ++i) {
            float xt   = buf[i];
            float var  = fmaxf(fmaf(-mean, mean, sq), 1e-4f);
            float rs   = rcp_f(sqrt_f(var) + 1e-5f);
            float a    = c1l * fabsf(xt - mean) * rs;
            float r1   = rcp_f(1.0f + exp2_f(a));
            float gate = fmaf(gA, r1, gB);
            __builtin_nontemporal_store(emit(xt, gate), pout + i * D_DIM);
            mean = fmaf(dl, mean, ql * xt);
            sq   = fmaf(dl, sq,   ql * (xt * xt));
        }
        pout += G * D_DIM;

        #pragma unroll
        for (int i = 0; i < G; ++i) buf[i] = nbuf[i];
    }

    // last group
    #pragma unroll
    for (int i = 0; i < G; ++i) {
        float xt   = buf[i];
        float var  = fmaxf(fmaf(-mean, mean, sq), 1e-4f);
        float rs   = rcp_f(sqrt_f(var) + 1e-5f);
        float a    = c1l * fabsf(xt - mean) * rs;
        float r1   = rcp_f(1.0f + exp2_f(a));
        float gate = fmaf(gA, r1, gB);
        __builtin_nontemporal_store(emit(xt, gate), pout + i * D_DIM);
        mean = fmaf(dl, mean, ql * xt);
        sq   = fmaf(dl, sq,   ql * (xt * xt));
    }
}

extern "C" void kernel_launch(void* const* d_in, const int* in_sizes, int n_in,
                              void* d_out, int out_size, void* d_ws, size_t ws_size,
                              hipStream_t stream) {
    const float* x = (const float*)d_in[0];
    // dict order: x, logit_decay_l, log_sigma_l, log_alpha_l,
    //             logit_decay_g(unused), log_sigma_g, log_alpha_g, ema_mean_g, ema_sq_g
    gelu130_kernel<<<dim3(B_DIM * NCHUNK * DTILES), dim3(256), 0, stream>>>(
        x,
        (const float*)d_in[1],
        (const float*)d_in[2],
        (const float*)d_in[3],
        (const float*)d_in[5],
        (const float*)d_in[6],
        (const float*)d_in[7],
        (const float*)d_in[8],
        (float*)d_out);
}